// Round 1
// baseline (213.171 us; speedup 1.0000x reference)
//
#include <hip/hip_runtime.h>
#include <math.h>

#define N_ 2048
#define R_ 64
#define D_ 64
#define K_ 512
#define M_ (N_*R_)      // 131072 rows
#define BM 128          // rows per block in argmin kernel
#define LDW 132         // padded LDS stride (16B-aligned, float4-friendly)

// ws layout (floats): [0]=vq acc, [1]=orth acc, [16..527]=wn, [1024..5119]=gram

// ---------------------------------------------------------------- init + ||w||^2
__global__ void k_init(const float* __restrict__ w, float* __restrict__ ws) {
    int t = blockIdx.x * 256 + threadIdx.x;   // 0..511, one code each
    if (t < 16) ws[t] = 0.f;
    const float4* wr = (const float4*)(w + (long)t * 64);
    float s = 0.f;
#pragma unroll
    for (int i = 0; i < 16; ++i) {
        float4 v = wr[i];
        s += v.x*v.x + v.y*v.y + v.z*v.z + v.w*v.w;
    }
    ws[16 + t] = s;
}

// ---------------------------------------------------------------- argmin + gather
__global__ __launch_bounds__(256, 2) void k_argmin(
    const float* __restrict__ x, const float* __restrict__ w,
    const float* __restrict__ ws, float* __restrict__ out)
{
    __shared__ float XT[64][LDW];   // x transposed: [d][row]
    __shared__ float WT[64][LDW];   // w chunk transposed: [d][code]
    __shared__ float wn_s[128];
    __shared__ int   ridx[BM];

    const int t = threadIdx.x;
    const long base = (long)blockIdx.x * BM;

    // stage XT (transpose 128 rows x 64 dims)
#pragma unroll
    for (int i = 0; i < 8; ++i) {
        int f = i * 256 + t;
        int row = f >> 4, d = (f & 15) * 4;
        float4 v = *(const float4*)(x + (base + row) * 64 + d);
        XT[d+0][row] = v.x; XT[d+1][row] = v.y; XT[d+2][row] = v.z; XT[d+3][row] = v.w;
    }

    const int tm = t >> 4;   // row group: rows tm*8..tm*8+7
    const int tk = t & 15;   // code group: codes tk*4 and 64+tk*4 within chunk

    float bestv[8]; int besti[8];
#pragma unroll
    for (int i = 0; i < 8; ++i) { bestv[i] = 3.4e38f; besti[i] = 0; }

    for (int c = 0; c < 4; ++c) {
        const int cbase = c * 128;
        __syncthreads();   // XT ready (c=0) / previous chunk compute done
#pragma unroll
        for (int i = 0; i < 8; ++i) {
            int f = i * 256 + t;
            int code = f >> 4, d = (f & 15) * 4;
            float4 v = *(const float4*)(w + (long)(cbase + code) * 64 + d);
            WT[d+0][code] = v.x; WT[d+1][code] = v.y; WT[d+2][code] = v.z; WT[d+3][code] = v.w;
        }
        if (t < 128) wn_s[t] = ws[16 + cbase + t];
        __syncthreads();

        float accA[8][4], accB[8][4];
#pragma unroll
        for (int i = 0; i < 8; ++i)
#pragma unroll
            for (int j = 0; j < 4; ++j) { accA[i][j] = 0.f; accB[i][j] = 0.f; }

#pragma unroll 4
        for (int d = 0; d < 64; ++d) {
            const float4 xa = *(const float4*)&XT[d][tm*8];
            const float4 xb = *(const float4*)&XT[d][tm*8+4];
            const float4 wa = *(const float4*)&WT[d][tk*4];
            const float4 wb = *(const float4*)&WT[d][64 + tk*4];
            const float xr[8]  = {xa.x,xa.y,xa.z,xa.w,xb.x,xb.y,xb.z,xb.w};
            const float wva[4] = {wa.x,wa.y,wa.z,wa.w};
            const float wvb[4] = {wb.x,wb.y,wb.z,wb.w};
#pragma unroll
            for (int i = 0; i < 8; ++i)
#pragma unroll
                for (int j = 0; j < 4; ++j) {
                    accA[i][j] = fmaf(xr[i], wva[j], accA[i][j]);
                    accB[i][j] = fmaf(xr[i], wvb[j], accB[i][j]);
                }
        }

#pragma unroll
        for (int j = 0; j < 4; ++j) {
            const int   cA = cbase + tk*4 + j,  cB = cbase + 64 + tk*4 + j;
            const float wnA = wn_s[tk*4 + j],   wnB = wn_s[64 + tk*4 + j];
#pragma unroll
            for (int i = 0; i < 8; ++i) {
                float sA = fmaf(-2.f, accA[i][j], wnA);
                if (sA < bestv[i] || (sA == bestv[i] && cA < besti[i])) { bestv[i] = sA; besti[i] = cA; }
                float sB = fmaf(-2.f, accB[i][j], wnB);
                if (sB < bestv[i] || (sB == bestv[i] && cB < besti[i])) { bestv[i] = sB; besti[i] = cB; }
            }
        }
    }

    // reduce (val,idx) across the 16 lanes sharing a row group (consecutive lanes)
#pragma unroll
    for (int m = 1; m < 16; m <<= 1) {
#pragma unroll
        for (int i = 0; i < 8; ++i) {
            float ov = __shfl_xor(bestv[i], m, 64);
            int   oi = __shfl_xor(besti[i], m, 64);
            if (ov < bestv[i] || (ov == bestv[i] && oi < besti[i])) { bestv[i] = ov; besti[i] = oi; }
        }
    }
    if (tk == 0)
#pragma unroll
        for (int i = 0; i < 8; ++i) ridx[tm*8 + i] = besti[i];
    __syncthreads();

    // outputs: q_sg, q (gather weight rows), filler_idxs
    float* q_sg = out + 5;
    float* q    = out + 5 + (long)M_ * 64;
    float* fidx = out + 5 + 2L * M_ * 64;
#pragma unroll
    for (int i = 0; i < 32; ++i) {
        int e = i * 256 + t;
        int r = e >> 6, d = e & 63;
        float v = w[(long)ridx[r] * 64 + d];
        long off = base * 64 + e;
        q_sg[off] = v; q[off] = v;
    }
    if (t < BM) fidx[base + t] = (float)ridx[t];
}

// ---------------------------------------------------------------- vq/commit loss
__global__ void k_vq(const float* __restrict__ x, const float* __restrict__ qv,
                     float* __restrict__ ws)
{
    __shared__ float red[4][64];
    const int n = blockIdx.x, t = threadIdx.x;
    const int d = t & 63, rg = t >> 6;
    const float* xb = x  + (long)n * R_ * 64;
    const float* qb = qv + (long)n * R_ * 64;
    float s = 0.f;
    for (int r = rg * 16; r < rg * 16 + 16; ++r) {
        float diff = qb[r*64 + d] - xb[r*64 + d];
        float p = diff * diff;
        s = fmaf(p, p, s);
    }
    red[rg][d] = s;
    __syncthreads();
    if (t < 64) {
        float tot = red[0][d] + red[1][d] + red[2][d] + red[3][d];
        float v = sqrtf(tot);
#pragma unroll
        for (int m = 1; m < 64; m <<= 1) v += __shfl_xor(v, m, 64);
        if (t == 0) atomicAdd(ws + 0, v);
    }
}

// ---------------------------------------------------------------- gram + orth
__global__ void k_gram(const float* __restrict__ w, float* __restrict__ ws)
{
    __shared__ float red[4][64];
    const int i = blockIdx.x, t = threadIdx.x;
    const int j = t & 63, kg = t >> 6;
    float s = 0.f;
    for (int k = kg * 128; k < kg * 128 + 128; ++k)
        s = fmaf(w[(long)k*64 + i], w[(long)k*64 + j], s);
    red[kg][j] = s;
    __syncthreads();
    if (t < 64) {
        float g = red[0][j] + red[1][j] + red[2][j] + red[3][j];
        ws[1024 + i*64 + j] = g;
        float p = g - (i == j ? 1.f : 0.f);
        float pp = p * p;
#pragma unroll
        for (int m = 1; m < 64; m <<= 1) pp += __shfl_xor(pp, m, 64);
        if (j == 0 && t < 64) atomicAdd(ws + 1, pp);
    }
}

// ---------------------------------------------------------------- rank + finalize
__global__ void k_final(const float* __restrict__ ws_in, float* __restrict__ ws,
                        float* __restrict__ out)
{
    __shared__ float g[64][65];
    __shared__ float fac[64];
    __shared__ float tol;
    __shared__ int   rankc;
    const int t = threadIdx.x;
    for (int i = t; i < 4096; i += 256) g[i >> 6][i & 63] = ws_in[1024 + i];
    if (t == 0) rankc = 0;
    __syncthreads();
    if (t == 0) {
        float maxd = 0.f;
        for (int i = 0; i < 64; ++i) maxd = fmaxf(maxd, fabsf(g[i][i]));
        tol = maxd * 1e-7f + 1e-30f;
    }
    __syncthreads();
    for (int s = 0; s < 64; ++s) {
        float p = g[s][s];
        bool ok = fabsf(p) > tol;
        if (t == 0 && ok) rankc++;
        if (t < 64) fac[t] = (ok && t > s) ? g[t][s] / p : 0.f;
        __syncthreads();
        const int j = t & 63, rq = t >> 6;
        float gsj = g[s][j];
        for (int r = s + 1 + rq; r < 64; r += 4)
            g[r][j] -= fac[r] * gsj;
        __syncthreads();
    }
    if (t == 0) {
        float vq = ws[0] / (float)(N_ * D_);     // mean over (N, D)
        float orth = sqrtf(ws[1]);
        out[0] = 1.0f * vq + 0.5f * vq + 0.0f * orth;
        out[1] = vq;
        out[2] = vq;
        out[3] = orth;
        out[4] = (float)rankc;
    }
}

// ---------------------------------------------------------------- launcher
extern "C" void kernel_launch(void* const* d_in, const int* in_sizes, int n_in,
                              void* d_out, int out_size, void* d_ws, size_t ws_size,
                              hipStream_t stream) {
    const float* x = (const float*)d_in[0];   // soft_fillers [N,R,D]
    const float* w = (const float*)d_in[1];   // weight [K,D]
    float* out = (float*)d_out;
    float* ws  = (float*)d_ws;

    hipLaunchKernelGGL(k_init,   dim3(2),      dim3(256), 0, stream, w, ws);
    hipLaunchKernelGGL(k_argmin, dim3(M_/BM),  dim3(256), 0, stream, x, w, ws, out);
    hipLaunchKernelGGL(k_vq,     dim3(N_),     dim3(256), 0, stream,
                       x, out + 5 + (long)M_ * 64, ws);
    hipLaunchKernelGGL(k_gram,   dim3(64),     dim3(256), 0, stream, w, ws);
    hipLaunchKernelGGL(k_final,  dim3(1),      dim3(256), 0, stream, ws, ws, out);
}